// Round 1
// baseline (130.590 us; speedup 1.0000x reference)
//
#include <hip/hip_runtime.h>
#include <stdint.h>

#define NN   100000
#define DEG  16
#define CH   128
#define TILE 64

typedef __attribute__((ext_vector_type(8))) short bf16x8;
typedef __attribute__((ext_vector_type(4))) float f32x4;

__device__ __forceinline__ uint32_t pack2_bf16(float a, float b) {
    uint32_t ua = __builtin_bit_cast(uint32_t, a);
    uint32_t ub = __builtin_bit_cast(uint32_t, b);
    ua = (ua + 0x7FFFu + ((ua >> 16) & 1u)) >> 16;   // RNE
    ub = (ub + 0x7FFFu + ((ub >> 16) & 1u)) >> 16;
    return ua | (ub << 16);
}

// LDS layouts: rows of 64 u32 (128 bf16). Swizzle: u32 idx ^= (row&7)<<2
// => byte ^= (row&7)<<4, keeps 16B granules intact for ds_read_b128,
// spreads 8 consecutive rows across all 32 banks.

__global__ __launch_bounds__(256, 3)
void gin_fused_kernel(const float* __restrict__ x,
                      const int*   __restrict__ edge,
                      const float* __restrict__ W,
                      const float* __restrict__ bias,
                      const float* __restrict__ epsp,
                      const float* __restrict__ gamma,
                      const float* __restrict__ beta,
                      float*       __restrict__ out)
{
    __shared__ uint32_t Wl[128 * 64];   // W^T as bf16 pairs: [n][k2], swizzled (32 KB)
    __shared__ uint32_t Hl[TILE * 64];  // h as bf16 pairs: [node][k2], swizzled (16 KB)

    const int t    = threadIdx.x;
    const int lane = t & 63;
    const int wv   = t >> 6;        // wave id 0..3
    const int cl   = lane & 15;
    const int g4   = lane >> 4;     // 0..3

    // ---- stage W^T bf16 into LDS (transpose-on-stage, coalesced global reads) ----
    #pragma unroll
    for (int j = 0; j < 32; ++j) {
        int e  = t + 256 * j;       // 0..8191
        int n  = e & 127;           // out-channel (row of W^T)
        int k2 = e >> 7;            // k-pair 0..63
        float a = W[(2 * k2)     * CH + n];
        float c = W[(2 * k2 + 1) * CH + n];
        Wl[n * 64 + (k2 ^ ((n & 7) << 2))] = pack2_bf16(a, c);
    }

    const float eps1 = 1.0f + epsp[0];
    float g_r[8], be_r[8], bi_r[8];
    #pragma unroll
    for (int ct = 0; ct < 8; ++ct) {
        g_r[ct]  = gamma[ct * 16 + cl];
        be_r[ct] = beta [ct * 16 + cl];
        bi_r[ct] = bias [ct * 16 + cl];
    }

    const int tile_base = blockIdx.x * TILE;

    // ---- phase A: gather + GIN combine -> Hl (wave w owns nodes 16w..16w+15) ----
    for (int i = 0; i < 16; ++i) {
        int row  = 16 * wv + i;
        int node = __builtin_amdgcn_readfirstlane(tile_base + row);
        float ax = 0.0f, ay = 0.0f;
        if (node < NN) {
            const int* ep = edge + (size_t)node * DEG;
            int idxs[DEG];
            #pragma unroll
            for (int d = 0; d < DEG; ++d) idxs[d] = ep[d];   // scalar loads (uniform)
            #pragma unroll
            for (int d = 0; d < DEG; ++d) {
                int  j  = idxs[d];
                bool ok = (j < NN);            // j == NN is the zero-padding row
                int  jc = ok ? j : 0;
                const float2 v = *reinterpret_cast<const float2*>(x + (size_t)jc * CH + 2 * lane);
                ax += ok ? v.x : 0.0f;
                ay += ok ? v.y : 0.0f;
            }
            const float2 xv = *reinterpret_cast<const float2*>(x + (size_t)node * CH + 2 * lane);
            ax += eps1 * xv.x;
            ay += eps1 * xv.y;
        }
        Hl[row * 64 + (lane ^ ((row & 7) << 2))] = pack2_bf16(ax, ay);
    }
    __syncthreads();

    // ---- phase B: h @ W via MFMA 16x16x32 bf16 ----
    // A-frag: lane holds h[node = 16w + (lane&15)][k = ks*32 + (lane>>4)*8 + j]
    const int arow = 16 * wv + cl;
    bf16x8 afr[4];
    #pragma unroll
    for (int ks = 0; ks < 4; ++ks) {
        int k2b = ks * 16 + g4 * 4;
        afr[ks] = *reinterpret_cast<const bf16x8*>(&Hl[arow * 64 + (k2b ^ ((arow & 7) << 2))]);
    }
    f32x4 acc[8];
    #pragma unroll
    for (int ct = 0; ct < 8; ++ct) acc[ct] = (f32x4){0.f, 0.f, 0.f, 0.f};
    #pragma unroll
    for (int ct = 0; ct < 8; ++ct) {
        int brow = ct * 16 + cl;     // out-channel (row of W^T) = B's n index
        #pragma unroll
        for (int ks = 0; ks < 4; ++ks) {
            int k2b = ks * 16 + g4 * 4;
            bf16x8 bfr = *reinterpret_cast<const bf16x8*>(&Wl[brow * 64 + (k2b ^ ((brow & 7) << 2))]);
            acc[ct] = __builtin_amdgcn_mfma_f32_16x16x32_bf16(afr[ks], bfr, acc[ct], 0, 0, 0);
        }
    }

    // ---- phase C: bias + LayerNorm + store ----
    // C/D layout: col = lane&15 (out-channel within ct), row = g4*4 + reg (node)
    float s1[4] = {0, 0, 0, 0}, s2[4] = {0, 0, 0, 0};
    #pragma unroll
    for (int ct = 0; ct < 8; ++ct) {
        #pragma unroll
        for (int r = 0; r < 4; ++r) {
            float v = acc[ct][r] + bi_r[ct];
            acc[ct][r] = v;
            s1[r] += v;
            s2[r] += v * v;
        }
    }
    #pragma unroll
    for (int m = 1; m < 16; m <<= 1) {
        #pragma unroll
        for (int r = 0; r < 4; ++r) {
            s1[r] += __shfl_xor(s1[r], m, 64);
            s2[r] += __shfl_xor(s2[r], m, 64);
        }
    }
    #pragma unroll
    for (int r = 0; r < 4; ++r) {
        int node = tile_base + 16 * wv + g4 * 4 + r;
        if (node < NN) {
            float mu  = s1[r] * (1.0f / CH);
            float var = s2[r] * (1.0f / CH) - mu * mu;
            float rs  = rsqrtf(var + 1e-5f);
            float* op = out + (size_t)node * CH + cl;
            #pragma unroll
            for (int ct = 0; ct < 8; ++ct) {
                op[ct * 16] = (acc[ct][r] - mu) * rs * g_r[ct] + be_r[ct];
            }
        }
    }
}

extern "C" void kernel_launch(void* const* d_in, const int* in_sizes, int n_in,
                              void* d_out, int out_size, void* d_ws, size_t ws_size,
                              hipStream_t stream) {
    const float* x     = (const float*)d_in[0];
    const int*   edge  = (const int*)  d_in[1];
    const float* W     = (const float*)d_in[2];
    const float* b     = (const float*)d_in[3];
    const float* eps   = (const float*)d_in[4];
    const float* gamma = (const float*)d_in[5];
    const float* beta  = (const float*)d_in[6];
    float*       out   = (float*)d_out;

    int grid = (NN + TILE - 1) / TILE;   // 1563
    gin_fused_kernel<<<grid, 256, 0, stream>>>(x, edge, W, b, eps, gamma, beta, out);
}

// Round 2
// 82.931 us; speedup vs baseline: 1.5747x; 1.5747x over previous
//
#include <hip/hip_runtime.h>
#include <stdint.h>

#define NN   100000
#define DEG  16
#define CH   128
#define TILE 64

typedef __attribute__((ext_vector_type(8))) short bf16x8;
typedef __attribute__((ext_vector_type(4))) float f32x4;

__device__ __forceinline__ uint32_t pack2_bf16(float a, float b) {
    uint32_t ua = __builtin_bit_cast(uint32_t, a);
    uint32_t ub = __builtin_bit_cast(uint32_t, b);
    ua = (ua + 0x7FFFu + ((ua >> 16) & 1u)) >> 16;   // RNE
    ub = (ub + 0x7FFFu + ((ub >> 16) & 1u)) >> 16;
    return ua | (ub << 16);
}
__device__ __forceinline__ float bf_lo(uint32_t w) { return __builtin_bit_cast(float, w << 16); }
__device__ __forceinline__ float bf_hi(uint32_t w) { return __builtin_bit_cast(float, w & 0xFFFF0000u); }

// ---- pre-pass: x (f32) -> bf16 table in ws, rows of 256B; row NN = zeros ----
__global__ __launch_bounds__(256)
void convert_x_kernel(const float* __restrict__ x, uint32_t* __restrict__ xbf) {
    const int total = NN * CH / 8;          // uint4 groups (each = 8 channels)
    for (int i = blockIdx.x * blockDim.x + threadIdx.x; i < total;
         i += gridDim.x * blockDim.x) {
        float4 a = ((const float4*)x)[2 * i];
        float4 b = ((const float4*)x)[2 * i + 1];
        uint4 o;
        o.x = pack2_bf16(a.x, a.y); o.y = pack2_bf16(a.z, a.w);
        o.z = pack2_bf16(b.x, b.y); o.w = pack2_bf16(b.z, b.w);
        ((uint4*)xbf)[i] = o;
    }
    if (blockIdx.x == 0 && threadIdx.x < CH / 8)   // zero padding row (index NN)
        ((uint4*)xbf)[NN * (CH / 8) + threadIdx.x] = make_uint4(0, 0, 0, 0);
}

// LDS layouts: rows of 64 u32 (128 bf16). Swizzle: u32 idx ^= (row&7)<<2
// (flips bits 2..4 -> preserves 16B granules for ds_read_b128/ds_write_b128).

template <int BF>
__global__ __launch_bounds__(256, 3)
void gin_fused_kernel(const float* __restrict__ x,
                      const uint32_t* __restrict__ xbf,
                      const int*   __restrict__ edge,
                      const float* __restrict__ W,
                      const float* __restrict__ bias,
                      const float* __restrict__ epsp,
                      const float* __restrict__ gamma,
                      const float* __restrict__ beta,
                      float*       __restrict__ out)
{
    __shared__ uint32_t Wl[128 * 64];   // W^T as bf16 pairs, swizzled (32 KB)
    __shared__ uint32_t Hl[TILE * 64];  // h as bf16 pairs, swizzled (16 KB)

    const int t    = threadIdx.x;
    const int lane = t & 63;
    const int wv   = t >> 6;
    const int cl   = lane & 15;
    const int g4   = lane >> 4;

    // ---- stage W^T bf16 into LDS ----
    #pragma unroll
    for (int j = 0; j < 32; ++j) {
        int e  = t + 256 * j;
        int n  = e & 127;
        int k2 = e >> 7;
        float a = W[(2 * k2)     * CH + n];
        float c = W[(2 * k2 + 1) * CH + n];
        Wl[n * 64 + (k2 ^ ((n & 7) << 2))] = pack2_bf16(a, c);
    }

    const float eps1 = 1.0f + epsp[0];
    float g_r[8], be_r[8], bi_r[8];
    #pragma unroll
    for (int ct = 0; ct < 8; ++ct) {
        g_r[ct]  = gamma[ct * 16 + cl];
        be_r[ct] = beta [ct * 16 + cl];
        bi_r[ct] = bias [ct * 16 + cl];
    }

    const int tile_base = blockIdx.x * TILE;
    const uint4* xb4 = (const uint4*)xbf;

    // ---- phase A: gather + GIN combine -> Hl ----
    // quarter-wave per node: sub = lane>>4 owns node row 16*wv + 4*it + sub,
    // lane handles channels cl*8 .. cl*8+7 (16B per gather row).
    #pragma unroll
    for (int it = 0; it < 4; ++it) {
        const int row  = 16 * wv + 4 * it + g4;
        const int node = tile_base + row;
        const bool nvalid = node < NN;
        // per-lane edge index: this lane's subgroup-node, neighbor #cl
        int j_all = edge[(size_t)(nvalid ? node : 0) * DEG + cl];

        float acc[8] = {0, 0, 0, 0, 0, 0, 0, 0};
        #pragma unroll
        for (int d = 0; d < DEG; ++d) {
            int j = __shfl(j_all, g4 * 16 + d, 64);   // idx d of my subgroup
            if (BF) {
                uint4 v = xb4[(size_t)j * (CH / 8) + cl];  // j==NN -> zero row
                acc[0] += bf_lo(v.x); acc[1] += bf_hi(v.x);
                acc[2] += bf_lo(v.y); acc[3] += bf_hi(v.y);
                acc[4] += bf_lo(v.z); acc[5] += bf_hi(v.z);
                acc[6] += bf_lo(v.w); acc[7] += bf_hi(v.w);
            } else {
                bool ok = j < NN;
                size_t jc = ok ? (size_t)j : 0;
                float4 a = ((const float4*)x)[jc * (CH / 4) + cl * 2];
                float4 b = ((const float4*)x)[jc * (CH / 4) + cl * 2 + 1];
                float m = ok ? 1.0f : 0.0f;
                acc[0] += m * a.x; acc[1] += m * a.y;
                acc[2] += m * a.z; acc[3] += m * a.w;
                acc[4] += m * b.x; acc[5] += m * b.y;
                acc[6] += m * b.z; acc[7] += m * b.w;
            }
        }
        // own row, scaled by (1+eps)
        if (BF) {
            size_t nz = nvalid ? (size_t)node : (size_t)NN;  // zero row if tail
            uint4 v = xb4[nz * (CH / 8) + cl];
            acc[0] += eps1 * bf_lo(v.x); acc[1] += eps1 * bf_hi(v.x);
            acc[2] += eps1 * bf_lo(v.y); acc[3] += eps1 * bf_hi(v.y);
            acc[4] += eps1 * bf_lo(v.z); acc[5] += eps1 * bf_hi(v.z);
            acc[6] += eps1 * bf_lo(v.w); acc[7] += eps1 * bf_hi(v.w);
        } else if (nvalid) {
            float4 a = ((const float4*)x)[(size_t)node * (CH / 4) + cl * 2];
            float4 b = ((const float4*)x)[(size_t)node * (CH / 4) + cl * 2 + 1];
            acc[0] += eps1 * a.x; acc[1] += eps1 * a.y;
            acc[2] += eps1 * a.z; acc[3] += eps1 * a.w;
            acc[4] += eps1 * b.x; acc[5] += eps1 * b.y;
            acc[6] += eps1 * b.z; acc[7] += eps1 * b.w;
        }
        uint4 hv;
        hv.x = pack2_bf16(acc[0], acc[1]); hv.y = pack2_bf16(acc[2], acc[3]);
        hv.z = pack2_bf16(acc[4], acc[5]); hv.w = pack2_bf16(acc[6], acc[7]);
        int hidx = row * 64 + ((cl * 4) ^ ((row & 7) << 2));  // 4-aligned
        ((uint4*)Hl)[hidx >> 2] = hv;
    }
    __syncthreads();

    // ---- phase B: h @ W via MFMA 16x16x32 bf16 ----
    const int arow = 16 * wv + cl;
    bf16x8 afr[4];
    #pragma unroll
    for (int ks = 0; ks < 4; ++ks) {
        int k2b = ks * 16 + g4 * 4;
        afr[ks] = *reinterpret_cast<const bf16x8*>(&Hl[arow * 64 + (k2b ^ ((arow & 7) << 2))]);
    }
    f32x4 acc[8];
    #pragma unroll
    for (int ct = 0; ct < 8; ++ct) acc[ct] = (f32x4){0.f, 0.f, 0.f, 0.f};
    #pragma unroll
    for (int ct = 0; ct < 8; ++ct) {
        int brow = ct * 16 + cl;
        #pragma unroll
        for (int ks = 0; ks < 4; ++ks) {
            int k2b = ks * 16 + g4 * 4;
            bf16x8 bfr = *reinterpret_cast<const bf16x8*>(&Wl[brow * 64 + (k2b ^ ((brow & 7) << 2))]);
            acc[ct] = __builtin_amdgcn_mfma_f32_16x16x32_bf16(afr[ks], bfr, acc[ct], 0, 0, 0);
        }
    }

    // ---- phase C: bias + LayerNorm + store ----
    float s1[4] = {0, 0, 0, 0}, s2[4] = {0, 0, 0, 0};
    #pragma unroll
    for (int ct = 0; ct < 8; ++ct) {
        #pragma unroll
        for (int r = 0; r < 4; ++r) {
            float v = acc[ct][r] + bi_r[ct];
            acc[ct][r] = v;
            s1[r] += v;
            s2[r] += v * v;
        }
    }
    #pragma unroll
    for (int m = 1; m < 16; m <<= 1) {
        #pragma unroll
        for (int r = 0; r < 4; ++r) {
            s1[r] += __shfl_xor(s1[r], m, 64);
            s2[r] += __shfl_xor(s2[r], m, 64);
        }
    }
    #pragma unroll
    for (int r = 0; r < 4; ++r) {
        int node = tile_base + 16 * wv + g4 * 4 + r;
        if (node < NN) {
            float mu  = s1[r] * (1.0f / CH);
            float var = s2[r] * (1.0f / CH) - mu * mu;
            float rs  = rsqrtf(var + 1e-5f);
            float* op = out + (size_t)node * CH + cl;
            #pragma unroll
            for (int ct = 0; ct < 8; ++ct) {
                op[ct * 16] = (acc[ct][r] - mu) * rs * g_r[ct] + be_r[ct];
            }
        }
    }
}

extern "C" void kernel_launch(void* const* d_in, const int* in_sizes, int n_in,
                              void* d_out, int out_size, void* d_ws, size_t ws_size,
                              hipStream_t stream) {
    const float* x     = (const float*)d_in[0];
    const int*   edge  = (const int*)  d_in[1];
    const float* W     = (const float*)d_in[2];
    const float* b     = (const float*)d_in[3];
    const float* eps   = (const float*)d_in[4];
    const float* gamma = (const float*)d_in[5];
    const float* beta  = (const float*)d_in[6];
    float*       out   = (float*)d_out;

    const int grid = (NN + TILE - 1) / TILE;   // 1563
    const size_t need = (size_t)(NN + 1) * CH * 2;   // bf16 table incl. zero row

    if (ws_size >= need) {
        uint32_t* xbf = (uint32_t*)d_ws;
        convert_x_kernel<<<2048, 256, 0, stream>>>(x, xbf);
        gin_fused_kernel<1><<<grid, 256, 0, stream>>>(x, xbf, edge, W, b, eps, gamma, beta, out);
    } else {
        gin_fused_kernel<0><<<grid, 256, 0, stream>>>(x, nullptr, edge, W, b, eps, gamma, beta, out);
    }
}